// Round 8
// baseline (456.081 us; speedup 1.0000x reference)
//
#include <hip/hip_runtime.h>

#define QMAXF 127.0f
#define NBLK 896u
typedef int i32x4 __attribute__((ext_vector_type(4)));

__device__ __forceinline__ unsigned fkey(float f) {
  const unsigned b = __float_as_uint(f);
  return (b & 0x80000000u) ? ~b : (b | 0x80000000u);
}
__device__ __forceinline__ float fdec(unsigned u) {
  return __uint_as_float((u & 0x80000000u) ? (u & 0x7FFFFFFFu) : ~u);
}

__device__ __forceinline__ void soft_sync(unsigned* cnt, unsigned* gen) {
  __syncthreads();
  if (threadIdx.x == 0) {
    const unsigned g = __hip_atomic_load(gen, __ATOMIC_RELAXED, __HIP_MEMORY_SCOPE_AGENT);
    const unsigned a = __hip_atomic_fetch_add(cnt, 1u, __ATOMIC_ACQ_REL, __HIP_MEMORY_SCOPE_AGENT);
    if (a == NBLK - 1u) {
      __hip_atomic_store(cnt, 0u, __ATOMIC_RELAXED, __HIP_MEMORY_SCOPE_AGENT);
      __hip_atomic_fetch_add(gen, 1u, __ATOMIC_RELEASE, __HIP_MEMORY_SCOPE_AGENT);
    } else {
      while (__hip_atomic_load(gen, __ATOMIC_ACQUIRE, __HIP_MEMORY_SCOPE_AGENT) == g)
        __builtin_amdgcn_s_sleep(2);
    }
  }
  __syncthreads();
}

// ===== k1: per-channel min/max of x (blocks 0..2047) + prep (block 2048) =====
__global__ __launch_bounds__(256, 8) void k1_minmax(
    const float* __restrict__ x, const float* __restrict__ actsf,
    const float* __restrict__ bnw, const float* __restrict__ bnb,
    const float* __restrict__ bnm, const float* __restrict__ bnv,
    const float* __restrict__ cw, unsigned* __restrict__ chanKmx,
    unsigned* __restrict__ chanKmn, float* __restrict__ scq,
    float* __restrict__ shq, float* __restrict__ wsf,
    signed char* __restrict__ wq8) {
  const int t = threadIdx.x, b = blockIdx.x;
  if (b == 2048) {
    __shared__ float red[4];
    float scale, shift;
    {
#pragma clang fp contract(off)
      float inv = 1.0f / sqrtf(bnv[t] + 1e-5f);
      scale = bnw[t] * inv;
      float tmp = bnm[t] * scale;
      shift = bnb[t] - tmp;
    }
    float a = fabsf(scale);
    for (int o = 32; o > 0; o >>= 1) a = fmaxf(a, __shfl_xor(a, o));
    if ((t & 63) == 0) red[t >> 6] = a;
    __syncthreads();
    const float amax = fmaxf(fmaxf(red[0], red[1]), fmaxf(red[2], red[3]));
    const float bn_sf = amax / QMAXF;
    scq[t] = fminf(fmaxf(rintf(scale / bn_sf), -128.f), 127.f) * bn_sf;
    const float bias_sf = bn_sf * actsf[0];
    shq[t] = rintf(shift / bias_sf) * bias_sf;
    // weight quant: 2 threads per output row
    const int r = t >> 1, half = t & 1;
    const float4* wrow = (const float4*)(cw + r * 256 + half * 128);
    float mx = 0.f;
#pragma unroll
    for (int j = 0; j < 32; ++j) {
      const float4 v = wrow[j];
      mx = fmaxf(mx, fmaxf(fmaxf(fabsf(v.x), fabsf(v.y)), fmaxf(fabsf(v.z), fabsf(v.w))));
    }
    mx = fmaxf(mx, __shfl_xor(mx, 1));
    const float wsf_v = mx / QMAXF;
    if (half == 0) wsf[r] = wsf_v;
    int* w8w = (int*)wq8;
#pragma unroll
    for (int j = 0; j < 32; ++j) {
      const float4 v = wrow[j];
      const float q0 = fminf(fmaxf(rintf(v.x / wsf_v), -128.f), 127.f);
      const float q1 = fminf(fmaxf(rintf(v.y / wsf_v), -128.f), 127.f);
      const float q2 = fminf(fmaxf(rintf(v.z / wsf_v), -128.f), 127.f);
      const float q3 = fminf(fmaxf(rintf(v.w / wsf_v), -128.f), 127.f);
      w8w[r * 64 + half * 32 + j] =
          ((int)q0 & 255) | (((int)q1 & 255) << 8) | (((int)q2 & 255) << 16) | (((int)q3 & 255) << 24);
    }
    return;
  }
  __shared__ float redmn[4][8], redmx[4][8];
  const int n = b >> 5, cg = b & 31;
  const float4* __restrict__ x4 = (const float4*)x + (long)(n * 256 + cg * 8) * 784;
  float mn[8], mx[8];
#pragma unroll
  for (int r = 0; r < 8; ++r) { mn[r] = __builtin_inff(); mx[r] = -__builtin_inff(); }
#pragma unroll
  for (int r = 0; r < 8; ++r) {
    const float4* row = x4 + r * 784;
    for (int j = t; j < 784; j += 256) {
      const float4 v = row[j];
      mn[r] = fminf(mn[r], fminf(fminf(v.x, v.y), fminf(v.z, v.w)));
      mx[r] = fmaxf(mx[r], fmaxf(fmaxf(v.x, v.y), fmaxf(v.z, v.w)));
    }
  }
#pragma unroll
  for (int r = 0; r < 8; ++r)
    for (int o = 32; o > 0; o >>= 1) {
      mn[r] = fminf(mn[r], __shfl_xor(mn[r], o));
      mx[r] = fmaxf(mx[r], __shfl_xor(mx[r], o));
    }
  if ((t & 63) == 0) {
#pragma unroll
    for (int r = 0; r < 8; ++r) { redmn[t >> 6][r] = mn[r]; redmx[t >> 6][r] = mx[r]; }
  }
  __syncthreads();
  if (t < 8) {
    const float fmn = fminf(fminf(redmn[0][t], redmn[1][t]), fminf(redmn[2][t], redmn[3][t]));
    const float fmx = fmaxf(fmaxf(redmx[0][t], redmx[1][t]), fmaxf(redmx[2][t], redmx[3][t]));
    atomicMax(&chanKmx[cg * 8 + t], fkey(fmx));
    atomicMax(&chanKmn[cg * 8 + t], ~fkey(fmn));
  }
}

// ===== k23: persistent fused P2 (quantize+xqT+MFMA+max) / barrier / P3 (GEMM+requant+pool) =====
// 896 blocks, exactly 2 tiles (112hw x 256ci) per block in each phase.
union K23Lds {
  int sw[112 * 64];        // 28 KB   P2 staged x_q ints, [hw][16 slots of 16B], slot^(hw&7)
  _Float16 q2[128 * 116];  // 29.75KB P3 quantized y ints for pooling
};

__global__ __launch_bounds__(256, 4) void k23(
    const float* __restrict__ x, const float* __restrict__ scq,
    const float* __restrict__ shq, const unsigned* __restrict__ chanKmx,
    const unsigned* __restrict__ chanKmn, const signed char* __restrict__ wq8,
    const float* __restrict__ wsf, signed char* __restrict__ xqT,
    unsigned* __restrict__ cnt, unsigned* __restrict__ gen,
    unsigned* __restrict__ gmax2K, float* __restrict__ out,
    float* __restrict__ outsf2) {
  __shared__ K23Lds lds;
  __shared__ float comax[128];
  __shared__ float red[4];
  __shared__ float sf1s;
  const int t = threadIdx.x, b = blockIdx.x;
  const int w = t >> 6, l = t & 63, m = l & 15, g = l >> 4;

  // ---- sf1 from channel extremes (exact: z monotone in x per channel) ----
  {
    const float s = scq[t], sh = shq[t];
    const float xe = (s >= 0.f) ? fdec(chanKmx[t]) : fdec(~chanKmn[t]);
    float z;
    {
#pragma clang fp contract(off)
      z = xe * s + sh;
    }
    float mm = fmaxf(z, 0.f);
    for (int o = 32; o > 0; o >>= 1) mm = fmaxf(mm, __shfl_xor(mm, o));
    if (l == 0) red[w] = mm;
    __syncthreads();
    if (t == 0) sf1s = fmaxf(fmaxf(red[0], red[1]), fmaxf(red[2], red[3])) / QMAXF;
    __syncthreads();
  }
  const float sf1 = sf1s;

  // ================= P2: two tiles per block =================
  for (int vb = b; vb < 1792; vb += (int)NBLK) {
    const int n = vb / 28, tt = vb - n * 28;
    const float* __restrict__ xb = x + (long)n * 802816 + tt * 112;
    signed char* __restrict__ dst = xqT + ((long)(n * 3136 + tt * 112)) * 256;
    for (int it = 0; it < 2; ++it) {
      const int task = it * 256 + t;
      if (task < 448) {
        const int slot = task & 15, hwq = task >> 4;
        const int hw0 = hwq * 4, ci0 = slot * 16;
        int wbuf[4][4] = {{0, 0, 0, 0}, {0, 0, 0, 0}, {0, 0, 0, 0}, {0, 0, 0, 0}};
#pragma unroll
        for (int j = 0; j < 16; ++j) {
          const float4 v = *(const float4*)(xb + (long)(ci0 + j) * 3136 + hw0);
          const float s = scq[ci0 + j], sh = shq[ci0 + j];
          float z0, z1, z2, z3;
          {
#pragma clang fp contract(off)
            z0 = v.x * s + sh; z1 = v.y * s + sh; z2 = v.z * s + sh; z3 = v.w * s + sh;
          }
          const float q0 = fminf(fmaxf(rintf(fmaxf(z0, 0.f) / sf1), -128.f), 127.f);
          const float q1 = fminf(fmaxf(rintf(fmaxf(z1, 0.f) / sf1), -128.f), 127.f);
          const float q2 = fminf(fmaxf(rintf(fmaxf(z2, 0.f) / sf1), -128.f), 127.f);
          const float q3 = fminf(fmaxf(rintf(fmaxf(z3, 0.f) / sf1), -128.f), 127.f);
          wbuf[0][j >> 2] |= ((int)q0 & 255) << ((j & 3) * 8);
          wbuf[1][j >> 2] |= ((int)q1 & 255) << ((j & 3) * 8);
          wbuf[2][j >> 2] |= ((int)q2 & 255) << ((j & 3) * 8);
          wbuf[3][j >> 2] |= ((int)q3 & 255) << ((j & 3) * 8);
        }
#pragma unroll
        for (int dh = 0; dh < 4; ++dh) {
          const int hw = hw0 + dh;
          *(i32x4*)&lds.sw[hw * 64 + ((slot ^ (hw & 7)) << 2)] = *(const i32x4*)wbuf[dh];
          *(i32x4*)(dst + hw * 256 + slot * 16) = *(const i32x4*)wbuf[dh];
        }
      }
    }
    __syncthreads();
    // int8 MFMA from LDS
    i32x4 acc[2][7];
#pragma unroll
    for (int ct = 0; ct < 2; ++ct)
#pragma unroll
      for (int ht = 0; ht < 7; ++ht) acc[ct][ht] = (i32x4){0, 0, 0, 0};
#pragma unroll
    for (int ks = 0; ks < 4; ++ks) {
      const i32x4 wf0 = *(const i32x4*)(wq8 + (w * 32 + m) * 256 + ks * 64 + g * 16);
      const i32x4 wf1 = *(const i32x4*)(wq8 + (w * 32 + 16 + m) * 256 + ks * 64 + g * 16);
#pragma unroll
      for (int ht = 0; ht < 7; ++ht) {
        const int row = ht * 16 + m;
        const i32x4 xf = *(const i32x4*)&lds.sw[row * 64 + (((ks * 4 + g) ^ (row & 7)) << 2)];
        acc[0][ht] = __builtin_amdgcn_mfma_i32_16x16x64_i8(wf0, xf, acc[0][ht], 0, 0, 0);
        acc[1][ht] = __builtin_amdgcn_mfma_i32_16x16x64_i8(wf1, xf, acc[1][ht], 0, 0, 0);
      }
    }
    // per-co |y_int| max
    int im[2][4];
#pragma unroll
    for (int ct = 0; ct < 2; ++ct)
#pragma unroll
      for (int r = 0; r < 4; ++r) {
        int v = 0;
#pragma unroll
        for (int ht = 0; ht < 7; ++ht) {
          int a = acc[ct][ht][r];
          a = a < 0 ? -a : a;
          v = a > v ? a : v;
        }
        im[ct][r] = v;
      }
#pragma unroll
    for (int o = 1; o < 16; o <<= 1)
#pragma unroll
      for (int ct = 0; ct < 2; ++ct)
#pragma unroll
        for (int r = 0; r < 4; ++r) {
          const int other = __shfl_xor(im[ct][r], o);
          im[ct][r] = other > im[ct][r] ? other : im[ct][r];
        }
    if (m == 0) {
#pragma unroll
      for (int ct = 0; ct < 2; ++ct)
#pragma unroll
        for (int r = 0; r < 4; ++r)
          comax[w * 32 + ct * 16 + g * 4 + r] = (float)im[ct][r];
    }
    __syncthreads();
    float v = 0.f;
    if (t < 128) v = comax[t] * (sf1 * wsf[t]);
    for (int o = 32; o > 0; o >>= 1) v = fmaxf(v, __shfl_xor(v, o));
    if (l == 0) red[w] = v;
    __syncthreads();
    if (t == 0)
      atomicMax(gmax2K, __float_as_uint(fmaxf(fmaxf(red[0], red[1]), fmaxf(red[2], red[3]))));
    __syncthreads();
  }
  soft_sync(cnt, gen);

  // ================= P3: two tiles per block =================
  const float sf2 =
      __uint_as_float(__hip_atomic_load(gmax2K, __ATOMIC_RELAXED, __HIP_MEMORY_SCOPE_AGENT)) / QMAXF;
  if (b == 0 && t == 0) outsf2[0] = sf2;
  for (int vb = b; vb < 1792; vb += (int)NBLK) {
    const int n = vb / 28, tt = vb - n * 28;
    const signed char* __restrict__ xb = xqT + ((long)(n * 3136 + tt * 112)) * 256;
    i32x4 acc[2][7];
#pragma unroll
    for (int ct = 0; ct < 2; ++ct)
#pragma unroll
      for (int ht = 0; ht < 7; ++ht) acc[ct][ht] = (i32x4){0, 0, 0, 0};
#pragma unroll
    for (int ks = 0; ks < 4; ++ks) {
      const i32x4 wf0 = *(const i32x4*)(wq8 + (w * 32 + m) * 256 + ks * 64 + g * 16);
      const i32x4 wf1 = *(const i32x4*)(wq8 + (w * 32 + 16 + m) * 256 + ks * 64 + g * 16);
#pragma unroll
      for (int ht = 0; ht < 7; ++ht) {
        const i32x4 xf = *(const i32x4*)(xb + (ht * 16 + m) * 256 + ks * 64 + g * 16);
        acc[0][ht] = __builtin_amdgcn_mfma_i32_16x16x64_i8(wf0, xf, acc[0][ht], 0, 0, 0);
        acc[1][ht] = __builtin_amdgcn_mfma_i32_16x16x64_i8(wf1, xf, acc[1][ht], 0, 0, 0);
      }
    }
    float fac[2][4];
#pragma unroll
    for (int ct = 0; ct < 2; ++ct)
#pragma unroll
      for (int r = 0; r < 4; ++r)
        fac[ct][r] = sf1 * wsf[w * 32 + ct * 16 + g * 4 + r];
#pragma unroll
    for (int ct = 0; ct < 2; ++ct)
#pragma unroll
      for (int ht = 0; ht < 7; ++ht)
#pragma unroll
        for (int r = 0; r < 4; ++r) {
          const float y = (float)acc[ct][ht][r] * fac[ct][r];
          const float q = fminf(fmaxf(rintf(y / sf2), -128.f), 127.f);
          lds.q2[(w * 32 + ct * 16 + g * 4 + r) * 116 + ht * 16 + m] = (_Float16)q;
        }
    __syncthreads();
    const long obase = (long)n * 100352 + tt * 28;
    for (int i = t; i < 3584; i += 256) {
      const unsigned co = (unsigned)i / 28u;
      const unsigned wo = (unsigned)i - co * 28u;
      const _Float16* row = lds.q2 + co * 116;
      const float a = (float)row[2 * wo] + (float)row[2 * wo + 1] +
                      (float)row[56 + 2 * wo] + (float)row[56 + 2 * wo + 1];
      out[obase + (long)co * 784 + wo] = rintf(a * 0.25f) * sf2;
    }
    __syncthreads();
  }
}

extern "C" void kernel_launch(void* const* d_in, const int* in_sizes, int n_in,
                              void* d_out, int out_size, void* d_ws, size_t ws_size,
                              hipStream_t stream) {
  const float* x     = (const float*)d_in[0];
  const float* actsf = (const float*)d_in[1];
  const float* bnw   = (const float*)d_in[2];
  const float* bnb   = (const float*)d_in[3];
  const float* bnm   = (const float*)d_in[4];
  const float* bnv   = (const float*)d_in[5];
  const float* cw    = (const float*)d_in[6];
  float* out = (float*)d_out;
  char* ws = (char*)d_ws;

  unsigned* cnt       = (unsigned*)ws;                 // 4 B   (memset 0)
  unsigned* gen       = (unsigned*)(ws + 4);           // 4 B   (memset 0)
  unsigned* gmax2K    = (unsigned*)(ws + 8);           // 4 B   (memset 0)
  unsigned* chanKmx   = (unsigned*)(ws + 256);         // 1 KB  (memset 0)
  unsigned* chanKmn   = (unsigned*)(ws + 1280);        // 1 KB  (memset 0)
  float* scq          = (float*)(ws + 4096);           // 1 KB
  float* shq          = (float*)(ws + 5120);           // 1 KB
  float* wsf          = (float*)(ws + 6144);           // 512 B
  signed char* wq8    = (signed char*)(ws + 8192);     // 32 KB
  signed char* xqT    = (signed char*)(ws + 65536);    // 51.4 MB (N,HW,C int8)
  float* outsf2       = out + (out_size - 1);

  hipMemsetAsync(ws, 0, 4096, stream);
  hipLaunchKernelGGL(k1_minmax, dim3(2049), dim3(256), 0, stream,
                     x, actsf, bnw, bnb, bnm, bnv, cw, chanKmx, chanKmn, scq, shq, wsf, wq8);
  hipLaunchKernelGGL(k23, dim3(NBLK), dim3(256), 0, stream,
                     x, scq, shq, chanKmx, chanKmn, wq8, wsf, xqT,
                     cnt, gen, gmax2K, out, outsf2);
}

// Round 9
// 159.798 us; speedup vs baseline: 2.8541x; 2.8541x over previous
//
#include <hip/hip_runtime.h>

#define QMAXF 127.0f
typedef int i32x4 __attribute__((ext_vector_type(4)));

__device__ __forceinline__ unsigned fkey(float f) {
  const unsigned b = __float_as_uint(f);
  return (b & 0x80000000u) ? ~b : (b | 0x80000000u);
}
__device__ __forceinline__ float fdec(unsigned u) {
  return __uint_as_float((u & 0x80000000u) ? (u & 0x7FFFFFFFu) : ~u);
}

// ===== k0_zero: zero the 4KB atomic/flag region (replaces hipMemsetAsync) =====
__global__ __launch_bounds__(256) void k0_zero(unsigned* __restrict__ p) {
  const int t = threadIdx.x;
  p[t] = 0u; p[t + 256] = 0u; p[t + 512] = 0u; p[t + 768] = 0u;
}

// ===== k1: per-channel min/max of x (blocks 0..2047) + prep (block 2048) =====
__global__ __launch_bounds__(256, 8) void k1_minmax(
    const float* __restrict__ x, const float* __restrict__ actsf,
    const float* __restrict__ bnw, const float* __restrict__ bnb,
    const float* __restrict__ bnm, const float* __restrict__ bnv,
    const float* __restrict__ cw, unsigned* __restrict__ chanKmx,
    unsigned* __restrict__ chanKmn, float* __restrict__ scq,
    float* __restrict__ shq, float* __restrict__ wsf,
    signed char* __restrict__ wq8) {
  const int t = threadIdx.x, b = blockIdx.x;
  if (b == 2048) {
    // ---- BN fold: thread = channel ----
    __shared__ float red[4];
    float scale, shift;
    {
#pragma clang fp contract(off)
      float inv = 1.0f / sqrtf(bnv[t] + 1e-5f);
      scale = bnw[t] * inv;
      float tmp = bnm[t] * scale;
      shift = bnb[t] - tmp;
    }
    float a = fabsf(scale);
    for (int o = 32; o > 0; o >>= 1) a = fmaxf(a, __shfl_xor(a, o));
    if ((t & 63) == 0) red[t >> 6] = a;
    __syncthreads();
    const float amax = fmaxf(fmaxf(red[0], red[1]), fmaxf(red[2], red[3]));
    const float bn_sf = amax / QMAXF;
    scq[t] = fminf(fmaxf(rintf(scale / bn_sf), -128.f), 127.f) * bn_sf;
    const float bias_sf = bn_sf * actsf[0];
    shq[t] = rintf(shift / bias_sf) * bias_sf;
    // ---- weight quant: 2 threads per output row ----
    const int r = t >> 1, half = t & 1;
    const float4* wrow = (const float4*)(cw + r * 256 + half * 128);
    float mx = 0.f;
#pragma unroll
    for (int j = 0; j < 32; ++j) {
      const float4 v = wrow[j];
      mx = fmaxf(mx, fmaxf(fmaxf(fabsf(v.x), fabsf(v.y)), fmaxf(fabsf(v.z), fabsf(v.w))));
    }
    mx = fmaxf(mx, __shfl_xor(mx, 1));
    const float wsf_v = mx / QMAXF;
    if (half == 0) wsf[r] = wsf_v;
    int* w8w = (int*)wq8;
#pragma unroll
    for (int j = 0; j < 32; ++j) {
      const float4 v = wrow[j];
      const float q0 = fminf(fmaxf(rintf(v.x / wsf_v), -128.f), 127.f);
      const float q1 = fminf(fmaxf(rintf(v.y / wsf_v), -128.f), 127.f);
      const float q2 = fminf(fmaxf(rintf(v.z / wsf_v), -128.f), 127.f);
      const float q3 = fminf(fmaxf(rintf(v.w / wsf_v), -128.f), 127.f);
      w8w[r * 64 + half * 32 + j] =
          ((int)q0 & 255) | (((int)q1 & 255) << 8) | (((int)q2 & 255) << 16) | (((int)q3 & 255) << 24);
    }
    return;
  }
  // ---- per-channel raw min/max: block = (n, 8-channel group) ----
  __shared__ float redmn[4][8], redmx[4][8];
  const int n = b >> 5, cg = b & 31;
  const float4* __restrict__ x4 = (const float4*)x + (long)(n * 256 + cg * 8) * 784;
  float mn[8], mx[8];
#pragma unroll
  for (int r = 0; r < 8; ++r) { mn[r] = __builtin_inff(); mx[r] = -__builtin_inff(); }
#pragma unroll
  for (int r = 0; r < 8; ++r) {
    const float4* row = x4 + r * 784;
    for (int j = t; j < 784; j += 256) {
      const float4 v = row[j];
      mn[r] = fminf(mn[r], fminf(fminf(v.x, v.y), fminf(v.z, v.w)));
      mx[r] = fmaxf(mx[r], fmaxf(fmaxf(v.x, v.y), fmaxf(v.z, v.w)));
    }
  }
#pragma unroll
  for (int r = 0; r < 8; ++r)
    for (int o = 32; o > 0; o >>= 1) {
      mn[r] = fminf(mn[r], __shfl_xor(mn[r], o));
      mx[r] = fmaxf(mx[r], __shfl_xor(mx[r], o));
    }
  if ((t & 63) == 0) {
#pragma unroll
    for (int r = 0; r < 8; ++r) { redmn[t >> 6][r] = mn[r]; redmx[t >> 6][r] = mx[r]; }
  }
  __syncthreads();
  if (t < 8) {
    const float fmn = fminf(fminf(redmn[0][t], redmn[1][t]), fminf(redmn[2][t], redmn[3][t]));
    const float fmx = fmaxf(fmaxf(redmx[0][t], redmx[1][t]), fmaxf(redmx[2][t], redmx[3][t]));
    atomicMax(&chanKmx[cg * 8 + t], fkey(fmx));
    atomicMax(&chanKmn[cg * 8 + t], ~fkey(fmn));
  }
}

// ===== k2f: per-block sf1 + quantize + LDS + xqT(direct) + int8 MFMA + global max =====
// Tile: 64 hw x 256 ci. LDS [64 hw][16 slots of 16B], slot ^ (hw&7) swizzle.
__global__ __launch_bounds__(256, 4) void k2f_quant_gemm(
    const float* __restrict__ x, const float* __restrict__ scq,
    const float* __restrict__ shq, const unsigned* __restrict__ chanKmx,
    const unsigned* __restrict__ chanKmn, const signed char* __restrict__ wq8,
    const float* __restrict__ wsf, signed char* __restrict__ xqT,
    unsigned* __restrict__ gmax2K) {
  __shared__ int sw[64 * 64];  // 16 KB
  __shared__ float comax[128];
  __shared__ float red[4];
  __shared__ float sf1s;
  const int t = threadIdx.x, w = t >> 6, l = t & 63, m = l & 15, g = l >> 4;
  const int blk = blockIdx.x, n = blk / 49, tt = blk - n * 49;

  // ---- sf1 from channel extremes (exact: z monotone in x per channel) ----
  {
    const float s = scq[t], sh = shq[t];
    const float xe = (s >= 0.f) ? fdec(chanKmx[t]) : fdec(~chanKmn[t]);
    float z;
    {
#pragma clang fp contract(off)
      z = xe * s + sh;
    }
    float mm = fmaxf(z, 0.f);
    for (int o = 32; o > 0; o >>= 1) mm = fmaxf(mm, __shfl_xor(mm, o));
    if (l == 0) red[w] = mm;
    __syncthreads();
    if (t == 0) sf1s = fmaxf(fmaxf(red[0], red[1]), fmaxf(red[2], red[3])) / QMAXF;
    __syncthreads();
  }
  const float sf1 = sf1s;
  const float* __restrict__ xb = x + (long)n * 802816 + tt * 64;

  // ---- quantize: one task/thread (16 ci x 4 hw); write LDS (swizzled) + xqT direct ----
  signed char* __restrict__ dst = xqT + ((long)(n * 3136 + tt * 64)) * 256;
  {
    const int slot = t & 15, hwq = t >> 4;
    const int hw0 = hwq * 4, ci0 = slot * 16;
    int wbuf[4][4] = {{0, 0, 0, 0}, {0, 0, 0, 0}, {0, 0, 0, 0}, {0, 0, 0, 0}};
#pragma unroll
    for (int j = 0; j < 16; ++j) {
      const float4 v = *(const float4*)(xb + (long)(ci0 + j) * 3136 + hw0);
      const float s = scq[ci0 + j], sh = shq[ci0 + j];
      float z0, z1, z2, z3;
      {
#pragma clang fp contract(off)
        z0 = v.x * s + sh; z1 = v.y * s + sh; z2 = v.z * s + sh; z3 = v.w * s + sh;
      }
      const float q0 = fminf(fmaxf(rintf(fmaxf(z0, 0.f) / sf1), -128.f), 127.f);
      const float q1 = fminf(fmaxf(rintf(fmaxf(z1, 0.f) / sf1), -128.f), 127.f);
      const float q2 = fminf(fmaxf(rintf(fmaxf(z2, 0.f) / sf1), -128.f), 127.f);
      const float q3 = fminf(fmaxf(rintf(fmaxf(z3, 0.f) / sf1), -128.f), 127.f);
      wbuf[0][j >> 2] |= ((int)q0 & 255) << ((j & 3) * 8);
      wbuf[1][j >> 2] |= ((int)q1 & 255) << ((j & 3) * 8);
      wbuf[2][j >> 2] |= ((int)q2 & 255) << ((j & 3) * 8);
      wbuf[3][j >> 2] |= ((int)q3 & 255) << ((j & 3) * 8);
    }
#pragma unroll
    for (int dh = 0; dh < 4; ++dh) {
      const int hw = hw0 + dh;
      *(i32x4*)&sw[hw * 64 + ((slot ^ (hw & 7)) << 2)] = *(const i32x4*)wbuf[dh];
      *(i32x4*)(dst + hw * 256 + slot * 16) = *(const i32x4*)wbuf[dh];
    }
  }
  __syncthreads();

  // ---- int8 MFMA from LDS: 4 ht x 2 ct x 4 ks ----
  i32x4 acc[2][4];
#pragma unroll
  for (int ct = 0; ct < 2; ++ct)
#pragma unroll
    for (int ht = 0; ht < 4; ++ht) acc[ct][ht] = (i32x4){0, 0, 0, 0};
#pragma unroll
  for (int ks = 0; ks < 4; ++ks) {
    const i32x4 wf0 = *(const i32x4*)(wq8 + (w * 32 + m) * 256 + ks * 64 + g * 16);
    const i32x4 wf1 = *(const i32x4*)(wq8 + (w * 32 + 16 + m) * 256 + ks * 64 + g * 16);
#pragma unroll
    for (int ht = 0; ht < 4; ++ht) {
      const int row = ht * 16 + m;
      const i32x4 xf = *(const i32x4*)&sw[row * 64 + (((ks * 4 + g) ^ (row & 7)) << 2)];
      acc[0][ht] = __builtin_amdgcn_mfma_i32_16x16x64_i8(wf0, xf, acc[0][ht], 0, 0, 0);
      acc[1][ht] = __builtin_amdgcn_mfma_i32_16x16x64_i8(wf1, xf, acc[1][ht], 0, 0, 0);
    }
  }

  // ---- per-co |y_int| max -> scaled -> global atomic ----
  int im[2][4];
#pragma unroll
  for (int ct = 0; ct < 2; ++ct)
#pragma unroll
    for (int r = 0; r < 4; ++r) {
      int v = 0;
#pragma unroll
      for (int ht = 0; ht < 4; ++ht) {
        int a = acc[ct][ht][r];
        a = a < 0 ? -a : a;
        v = a > v ? a : v;
      }
      im[ct][r] = v;
    }
#pragma unroll
  for (int o = 1; o < 16; o <<= 1)
#pragma unroll
    for (int ct = 0; ct < 2; ++ct)
#pragma unroll
      for (int r = 0; r < 4; ++r) {
        const int other = __shfl_xor(im[ct][r], o);
        im[ct][r] = other > im[ct][r] ? other : im[ct][r];
      }
  if (m == 0) {
#pragma unroll
    for (int ct = 0; ct < 2; ++ct)
#pragma unroll
      for (int r = 0; r < 4; ++r)
        comax[w * 32 + ct * 16 + g * 4 + r] = (float)im[ct][r];
  }
  __syncthreads();
  float v = 0.f;
  if (t < 128) v = comax[t] * (sf1 * wsf[t]);
  for (int o = 32; o > 0; o >>= 1) v = fmaxf(v, __shfl_xor(v, o));
  if (l == 0) red[w] = v;
  __syncthreads();
  if (t == 0)
    atomicMax(gmax2K, __float_as_uint(fmaxf(fmaxf(red[0], red[1]), fmaxf(red[2], red[3]))));
}

// ===== k3: final int8 GEMM + requant + fused 2x2 pool =====
__global__ __launch_bounds__(256, 3) void k3_final(
    const signed char* __restrict__ xqT, const signed char* __restrict__ wq8,
    const float* __restrict__ wsf, const float* __restrict__ scq,
    const float* __restrict__ shq, const unsigned* __restrict__ chanKmx,
    const unsigned* __restrict__ chanKmn, const unsigned* __restrict__ gmax2K,
    float* __restrict__ out, float* __restrict__ outsf2) {
  __shared__ _Float16 q2[128 * 116];  // 29.75 KB
  __shared__ float red[4];
  __shared__ float sf1s;
  const int t = threadIdx.x, w = t >> 6, l = t & 63;
  const int m = l & 15, g = l >> 4;
  const int blk = blockIdx.x;
  const int n = blk / 28, tt = blk - n * 28;

  // ---- recompute sf1 (identical arithmetic to k2f) ----
  {
    const float s = scq[t], sh = shq[t];
    const float xe = (s >= 0.f) ? fdec(chanKmx[t]) : fdec(~chanKmn[t]);
    float z;
    {
#pragma clang fp contract(off)
      z = xe * s + sh;
    }
    float mm = fmaxf(z, 0.f);
    for (int o = 32; o > 0; o >>= 1) mm = fmaxf(mm, __shfl_xor(mm, o));
    if (l == 0) red[w] = mm;
    __syncthreads();
    if (t == 0) sf1s = fmaxf(fmaxf(red[0], red[1]), fmaxf(red[2], red[3])) / QMAXF;
    __syncthreads();
  }
  const float sf1 = sf1s;
  const float sf2 = __uint_as_float(*gmax2K) / QMAXF;
  if (blk == 0 && t == 0) outsf2[0] = sf2;

  const signed char* __restrict__ xb = xqT + ((long)(n * 3136 + tt * 112)) * 256;
  i32x4 acc[2][7];
#pragma unroll
  for (int ct = 0; ct < 2; ++ct)
#pragma unroll
    for (int ht = 0; ht < 7; ++ht) acc[ct][ht] = (i32x4){0, 0, 0, 0};
#pragma unroll
  for (int ks = 0; ks < 4; ++ks) {
    const i32x4 wf0 = *(const i32x4*)(wq8 + (w * 32 + m) * 256 + ks * 64 + g * 16);
    const i32x4 wf1 = *(const i32x4*)(wq8 + (w * 32 + 16 + m) * 256 + ks * 64 + g * 16);
#pragma unroll
    for (int ht = 0; ht < 7; ++ht) {
      const i32x4 xf = *(const i32x4*)(xb + (ht * 16 + m) * 256 + ks * 64 + g * 16);
      acc[0][ht] = __builtin_amdgcn_mfma_i32_16x16x64_i8(wf0, xf, acc[0][ht], 0, 0, 0);
      acc[1][ht] = __builtin_amdgcn_mfma_i32_16x16x64_i8(wf1, xf, acc[1][ht], 0, 0, 0);
    }
  }
  float fac[2][4];
#pragma unroll
  for (int ct = 0; ct < 2; ++ct)
#pragma unroll
    for (int r = 0; r < 4; ++r)
      fac[ct][r] = sf1 * wsf[w * 32 + ct * 16 + g * 4 + r];
#pragma unroll
  for (int ct = 0; ct < 2; ++ct)
#pragma unroll
    for (int ht = 0; ht < 7; ++ht)
#pragma unroll
      for (int r = 0; r < 4; ++r) {
        const float y = (float)acc[ct][ht][r] * fac[ct][r];
        const float q = fminf(fmaxf(rintf(y / sf2), -128.f), 127.f);
        q2[(w * 32 + ct * 16 + g * 4 + r) * 116 + ht * 16 + m] = (_Float16)q;
      }
  __syncthreads();
  const long obase = (long)n * 100352 + tt * 28;
  for (int i = t; i < 3584; i += 256) {
    const unsigned co = (unsigned)i / 28u;
    const unsigned wo = (unsigned)i - co * 28u;
    const _Float16* row = q2 + co * 116;
    const float a = (float)row[2 * wo] + (float)row[2 * wo + 1] +
                    (float)row[56 + 2 * wo] + (float)row[56 + 2 * wo + 1];
    out[obase + (long)co * 784 + wo] = rintf(a * 0.25f) * sf2;
  }
}

extern "C" void kernel_launch(void* const* d_in, const int* in_sizes, int n_in,
                              void* d_out, int out_size, void* d_ws, size_t ws_size,
                              hipStream_t stream) {
  const float* x     = (const float*)d_in[0];
  const float* actsf = (const float*)d_in[1];
  const float* bnw   = (const float*)d_in[2];
  const float* bnb   = (const float*)d_in[3];
  const float* bnm   = (const float*)d_in[4];
  const float* bnv   = (const float*)d_in[5];
  const float* cw    = (const float*)d_in[6];
  float* out = (float*)d_out;
  char* ws = (char*)d_ws;

  unsigned* gmax2K    = (unsigned*)ws;                 // 4 B      (zeroed by k0_zero)
  unsigned* chanKmx   = (unsigned*)(ws + 256);         // 1 KB     (zeroed by k0_zero)
  unsigned* chanKmn   = (unsigned*)(ws + 1280);        // 1 KB     (zeroed by k0_zero)
  float* scq          = (float*)(ws + 4096);           // 1 KB
  float* shq          = (float*)(ws + 5120);           // 1 KB
  float* wsf          = (float*)(ws + 6144);           // 512 B
  signed char* wq8    = (signed char*)(ws + 8192);     // 32 KB
  signed char* xqT    = (signed char*)(ws + 65536);    // 51.4 MB (N,HW,C int8)
  float* outsf2       = out + (out_size - 1);

  hipLaunchKernelGGL(k0_zero, dim3(1), dim3(256), 0, stream, (unsigned*)ws);
  hipLaunchKernelGGL(k1_minmax, dim3(2049), dim3(256), 0, stream,
                     x, actsf, bnw, bnb, bnm, bnv, cw, chanKmx, chanKmn, scq, shq, wsf, wq8);
  hipLaunchKernelGGL(k2f_quant_gemm, dim3(3136), dim3(256), 0, stream,
                     x, scq, shq, chanKmx, chanKmn, wq8, wsf, xqT, gmax2K);
  hipLaunchKernelGGL(k3_final, dim3(1792), dim3(256), 0, stream,
                     xqT, wq8, wsf, scq, shq, chanKmx, chanKmn, gmax2K, out, outsf2);
}

// Round 10
// 157.074 us; speedup vs baseline: 2.9036x; 1.0173x over previous
//
#include <hip/hip_runtime.h>

#define QMAXF 127.0f
typedef int i32x4 __attribute__((ext_vector_type(4)));

__device__ __forceinline__ unsigned fkey(float f) {
  const unsigned b = __float_as_uint(f);
  return (b & 0x80000000u) ? ~b : (b | 0x80000000u);
}
__device__ __forceinline__ float fdec(unsigned u) {
  return __uint_as_float((u & 0x80000000u) ? (u & 0x7FFFFFFFu) : ~u);
}

// ===== k0_zero: zero the 4KB atomic/flag region =====
__global__ __launch_bounds__(256) void k0_zero(unsigned* __restrict__ p) {
  const int t = threadIdx.x;
  p[t] = 0u; p[t + 256] = 0u; p[t + 512] = 0u; p[t + 768] = 0u;
}

// ===== k1: per-channel min/max of x (blocks 0..2047) + prep (block 2048) =====
__global__ __launch_bounds__(256, 8) void k1_minmax(
    const float* __restrict__ x, const float* __restrict__ actsf,
    const float* __restrict__ bnw, const float* __restrict__ bnb,
    const float* __restrict__ bnm, const float* __restrict__ bnv,
    const float* __restrict__ cw, unsigned* __restrict__ chanKmx,
    unsigned* __restrict__ chanKmn, float* __restrict__ scq,
    float* __restrict__ shq, float* __restrict__ wsf,
    signed char* __restrict__ wq8) {
  const int t = threadIdx.x, b = blockIdx.x;
  if (b == 2048) {
    // ---- BN fold: thread = channel ----
    __shared__ float red[4];
    float scale, shift;
    {
#pragma clang fp contract(off)
      float inv = 1.0f / sqrtf(bnv[t] + 1e-5f);
      scale = bnw[t] * inv;
      float tmp = bnm[t] * scale;
      shift = bnb[t] - tmp;
    }
    float a = fabsf(scale);
    for (int o = 32; o > 0; o >>= 1) a = fmaxf(a, __shfl_xor(a, o));
    if ((t & 63) == 0) red[t >> 6] = a;
    __syncthreads();
    const float amax = fmaxf(fmaxf(red[0], red[1]), fmaxf(red[2], red[3]));
    const float bn_sf = amax / QMAXF;
    scq[t] = fminf(fmaxf(rintf(scale / bn_sf), -128.f), 127.f) * bn_sf;
    const float bias_sf = bn_sf * actsf[0];
    shq[t] = rintf(shift / bias_sf) * bias_sf;
    // ---- weight quant: 2 threads per output row ----
    const int r = t >> 1, half = t & 1;
    const float4* wrow = (const float4*)(cw + r * 256 + half * 128);
    float mx = 0.f;
#pragma unroll
    for (int j = 0; j < 32; ++j) {
      const float4 v = wrow[j];
      mx = fmaxf(mx, fmaxf(fmaxf(fabsf(v.x), fabsf(v.y)), fmaxf(fabsf(v.z), fabsf(v.w))));
    }
    mx = fmaxf(mx, __shfl_xor(mx, 1));
    const float wsf_v = mx / QMAXF;
    if (half == 0) wsf[r] = wsf_v;
    int* w8w = (int*)wq8;
#pragma unroll
    for (int j = 0; j < 32; ++j) {
      const float4 v = wrow[j];
      const float q0 = fminf(fmaxf(rintf(v.x / wsf_v), -128.f), 127.f);
      const float q1 = fminf(fmaxf(rintf(v.y / wsf_v), -128.f), 127.f);
      const float q2 = fminf(fmaxf(rintf(v.z / wsf_v), -128.f), 127.f);
      const float q3 = fminf(fmaxf(rintf(v.w / wsf_v), -128.f), 127.f);
      w8w[r * 64 + half * 32 + j] =
          ((int)q0 & 255) | (((int)q1 & 255) << 8) | (((int)q2 & 255) << 16) | (((int)q3 & 255) << 24);
    }
    return;
  }
  // ---- per-channel raw min/max: block = (n, 8-channel group) ----
  __shared__ float redmn[4][8], redmx[4][8];
  const int n = b >> 5, cg = b & 31;
  const float4* __restrict__ x4 = (const float4*)x + (long)(n * 256 + cg * 8) * 784;
  float mn[8], mx[8];
#pragma unroll
  for (int r = 0; r < 8; ++r) { mn[r] = __builtin_inff(); mx[r] = -__builtin_inff(); }
#pragma unroll
  for (int r = 0; r < 8; ++r) {
    const float4* row = x4 + r * 784;
    for (int j = t; j < 784; j += 256) {
      const float4 v = row[j];
      mn[r] = fminf(mn[r], fminf(fminf(v.x, v.y), fminf(v.z, v.w)));
      mx[r] = fmaxf(mx[r], fmaxf(fmaxf(v.x, v.y), fmaxf(v.z, v.w)));
    }
  }
#pragma unroll
  for (int r = 0; r < 8; ++r)
    for (int o = 32; o > 0; o >>= 1) {
      mn[r] = fminf(mn[r], __shfl_xor(mn[r], o));
      mx[r] = fmaxf(mx[r], __shfl_xor(mx[r], o));
    }
  if ((t & 63) == 0) {
#pragma unroll
    for (int r = 0; r < 8; ++r) { redmn[t >> 6][r] = mn[r]; redmx[t >> 6][r] = mx[r]; }
  }
  __syncthreads();
  if (t < 8) {
    const float fmn = fminf(fminf(redmn[0][t], redmn[1][t]), fminf(redmn[2][t], redmn[3][t]));
    const float fmx = fmaxf(fmaxf(redmx[0][t], redmx[1][t]), fmaxf(redmx[2][t], redmx[3][t]));
    atomicMax(&chanKmx[cg * 8 + t], fkey(fmx));
    atomicMax(&chanKmn[cg * 8 + t], ~fkey(fmn));
  }
}

// ===== k2f: per-block sf1 + quantize + LDS + xqT(direct) + int8 MFMA + blockmax write =====
// Tile: 64 hw x 256 ci. LDS [64 hw][16 slots of 16B], slot ^ (hw&7) swizzle.
__global__ __launch_bounds__(256, 4) void k2f_quant_gemm(
    const float* __restrict__ x, const float* __restrict__ scq,
    const float* __restrict__ shq, const unsigned* __restrict__ chanKmx,
    const unsigned* __restrict__ chanKmn, const signed char* __restrict__ wq8,
    const float* __restrict__ wsf, signed char* __restrict__ xqT,
    float* __restrict__ blockmax) {
  __shared__ int sw[64 * 64];  // 16 KB
  __shared__ float comax[128];
  __shared__ float red[4];
  __shared__ float sf1s;
  const int t = threadIdx.x, w = t >> 6, l = t & 63, m = l & 15, g = l >> 4;
  const int blk = blockIdx.x, n = blk / 49, tt = blk - n * 49;

  // ---- sf1 from channel extremes (exact: z monotone in x per channel) ----
  {
    const float s = scq[t], sh = shq[t];
    const float xe = (s >= 0.f) ? fdec(chanKmx[t]) : fdec(~chanKmn[t]);
    float z;
    {
#pragma clang fp contract(off)
      z = xe * s + sh;
    }
    float mm = fmaxf(z, 0.f);
    for (int o = 32; o > 0; o >>= 1) mm = fmaxf(mm, __shfl_xor(mm, o));
    if (l == 0) red[w] = mm;
    __syncthreads();
    if (t == 0) sf1s = fmaxf(fmaxf(red[0], red[1]), fmaxf(red[2], red[3])) / QMAXF;
    __syncthreads();
  }
  const float sf1 = sf1s;
  const float* __restrict__ xb = x + (long)n * 802816 + tt * 64;

  // ---- quantize: one task/thread (16 ci x 4 hw); write LDS (swizzled) + xqT direct ----
  signed char* __restrict__ dst = xqT + ((long)(n * 3136 + tt * 64)) * 256;
  {
    const int slot = t & 15, hwq = t >> 4;
    const int hw0 = hwq * 4, ci0 = slot * 16;
    int wbuf[4][4] = {{0, 0, 0, 0}, {0, 0, 0, 0}, {0, 0, 0, 0}, {0, 0, 0, 0}};
#pragma unroll
    for (int j = 0; j < 16; ++j) {
      const float4 v = *(const float4*)(xb + (long)(ci0 + j) * 3136 + hw0);
      const float s = scq[ci0 + j], sh = shq[ci0 + j];
      float z0, z1, z2, z3;
      {
#pragma clang fp contract(off)
        z0 = v.x * s + sh; z1 = v.y * s + sh; z2 = v.z * s + sh; z3 = v.w * s + sh;
      }
      const float q0 = fminf(fmaxf(rintf(fmaxf(z0, 0.f) / sf1), -128.f), 127.f);
      const float q1 = fminf(fmaxf(rintf(fmaxf(z1, 0.f) / sf1), -128.f), 127.f);
      const float q2 = fminf(fmaxf(rintf(fmaxf(z2, 0.f) / sf1), -128.f), 127.f);
      const float q3 = fminf(fmaxf(rintf(fmaxf(z3, 0.f) / sf1), -128.f), 127.f);
      wbuf[0][j >> 2] |= ((int)q0 & 255) << ((j & 3) * 8);
      wbuf[1][j >> 2] |= ((int)q1 & 255) << ((j & 3) * 8);
      wbuf[2][j >> 2] |= ((int)q2 & 255) << ((j & 3) * 8);
      wbuf[3][j >> 2] |= ((int)q3 & 255) << ((j & 3) * 8);
    }
#pragma unroll
    for (int dh = 0; dh < 4; ++dh) {
      const int hw = hw0 + dh;
      *(i32x4*)&sw[hw * 64 + ((slot ^ (hw & 7)) << 2)] = *(const i32x4*)wbuf[dh];
      *(i32x4*)(dst + hw * 256 + slot * 16) = *(const i32x4*)wbuf[dh];
    }
  }
  __syncthreads();

  // ---- int8 MFMA from LDS: 4 ht x 2 ct x 4 ks ----
  i32x4 acc[2][4];
#pragma unroll
  for (int ct = 0; ct < 2; ++ct)
#pragma unroll
    for (int ht = 0; ht < 4; ++ht) acc[ct][ht] = (i32x4){0, 0, 0, 0};
#pragma unroll
  for (int ks = 0; ks < 4; ++ks) {
    const i32x4 wf0 = *(const i32x4*)(wq8 + (w * 32 + m) * 256 + ks * 64 + g * 16);
    const i32x4 wf1 = *(const i32x4*)(wq8 + (w * 32 + 16 + m) * 256 + ks * 64 + g * 16);
#pragma unroll
    for (int ht = 0; ht < 4; ++ht) {
      const int row = ht * 16 + m;
      const i32x4 xf = *(const i32x4*)&sw[row * 64 + (((ks * 4 + g) ^ (row & 7)) << 2)];
      acc[0][ht] = __builtin_amdgcn_mfma_i32_16x16x64_i8(wf0, xf, acc[0][ht], 0, 0, 0);
      acc[1][ht] = __builtin_amdgcn_mfma_i32_16x16x64_i8(wf1, xf, acc[1][ht], 0, 0, 0);
    }
  }

  // ---- per-co |y_int| max -> scaled -> private blockmax slot (no atomic) ----
  int im[2][4];
#pragma unroll
  for (int ct = 0; ct < 2; ++ct)
#pragma unroll
    for (int r = 0; r < 4; ++r) {
      int v = 0;
#pragma unroll
      for (int ht = 0; ht < 4; ++ht) {
        int a = acc[ct][ht][r];
        a = a < 0 ? -a : a;
        v = a > v ? a : v;
      }
      im[ct][r] = v;
    }
#pragma unroll
  for (int o = 1; o < 16; o <<= 1)
#pragma unroll
    for (int ct = 0; ct < 2; ++ct)
#pragma unroll
      for (int r = 0; r < 4; ++r) {
        const int other = __shfl_xor(im[ct][r], o);
        im[ct][r] = other > im[ct][r] ? other : im[ct][r];
      }
  if (m == 0) {
#pragma unroll
    for (int ct = 0; ct < 2; ++ct)
#pragma unroll
      for (int r = 0; r < 4; ++r)
        comax[w * 32 + ct * 16 + g * 4 + r] = (float)im[ct][r];
  }
  __syncthreads();
  float v = 0.f;
  if (t < 128) v = comax[t] * (sf1 * wsf[t]);
  for (int o = 32; o > 0; o >>= 1) v = fmaxf(v, __shfl_xor(v, o));
  if (l == 0) red[w] = v;
  __syncthreads();
  if (t == 0)
    blockmax[blk] = fmaxf(fmaxf(red[0], red[1]), fmaxf(red[2], red[3]));
}

// ===== k3: blockmax reduce + final int8 GEMM + requant + fused 2x2 pool =====
__global__ __launch_bounds__(256, 3) void k3_final(
    const signed char* __restrict__ xqT, const signed char* __restrict__ wq8,
    const float* __restrict__ wsf, const float* __restrict__ scq,
    const float* __restrict__ shq, const unsigned* __restrict__ chanKmx,
    const unsigned* __restrict__ chanKmn, const float* __restrict__ blockmax,
    float* __restrict__ out, float* __restrict__ outsf2) {
  __shared__ _Float16 q2[128 * 116];  // 29.75 KB
  __shared__ float red[4];
  __shared__ float sf1s, sf2s;
  const int t = threadIdx.x, w = t >> 6, l = t & 63;
  const int m = l & 15, g = l >> 4;
  const int blk = blockIdx.x;
  const int n = blk / 28, tt = blk - n * 28;

  // ---- recompute sf1 (identical arithmetic to k2f) ----
  {
    const float s = scq[t], sh = shq[t];
    const float xe = (s >= 0.f) ? fdec(chanKmx[t]) : fdec(~chanKmn[t]);
    float z;
    {
#pragma clang fp contract(off)
      z = xe * s + sh;
    }
    float mm = fmaxf(z, 0.f);
    for (int o = 32; o > 0; o >>= 1) mm = fmaxf(mm, __shfl_xor(mm, o));
    if (l == 0) red[w] = mm;
    __syncthreads();
    if (t == 0) sf1s = fmaxf(fmaxf(red[0], red[1]), fmaxf(red[2], red[3])) / QMAXF;
  }
  // ---- sf2 = max over 3136 block maxima (L2-hot) ----
  {
    float bm = 0.f;
    for (int i = t; i < 3136; i += 256) bm = fmaxf(bm, blockmax[i]);
    for (int o = 32; o > 0; o >>= 1) bm = fmaxf(bm, __shfl_xor(bm, o));
    __syncthreads();
    if (l == 0) red[w] = bm;
    __syncthreads();
    if (t == 0) sf2s = fmaxf(fmaxf(red[0], red[1]), fmaxf(red[2], red[3])) / QMAXF;
    __syncthreads();
  }
  const float sf1 = sf1s;
  const float sf2 = sf2s;
  if (blk == 0 && t == 0) outsf2[0] = sf2;

  const signed char* __restrict__ xb = xqT + ((long)(n * 3136 + tt * 112)) * 256;
  i32x4 acc[2][7];
#pragma unroll
  for (int ct = 0; ct < 2; ++ct)
#pragma unroll
    for (int ht = 0; ht < 7; ++ht) acc[ct][ht] = (i32x4){0, 0, 0, 0};
#pragma unroll
  for (int ks = 0; ks < 4; ++ks) {
    const i32x4 wf0 = *(const i32x4*)(wq8 + (w * 32 + m) * 256 + ks * 64 + g * 16);
    const i32x4 wf1 = *(const i32x4*)(wq8 + (w * 32 + 16 + m) * 256 + ks * 64 + g * 16);
#pragma unroll
    for (int ht = 0; ht < 7; ++ht) {
      const i32x4 xf = *(const i32x4*)(xb + (ht * 16 + m) * 256 + ks * 64 + g * 16);
      acc[0][ht] = __builtin_amdgcn_mfma_i32_16x16x64_i8(wf0, xf, acc[0][ht], 0, 0, 0);
      acc[1][ht] = __builtin_amdgcn_mfma_i32_16x16x64_i8(wf1, xf, acc[1][ht], 0, 0, 0);
    }
  }
  float fac[2][4];
#pragma unroll
  for (int ct = 0; ct < 2; ++ct)
#pragma unroll
    for (int r = 0; r < 4; ++r)
      fac[ct][r] = sf1 * wsf[w * 32 + ct * 16 + g * 4 + r];
#pragma unroll
  for (int ct = 0; ct < 2; ++ct)
#pragma unroll
    for (int ht = 0; ht < 7; ++ht)
#pragma unroll
      for (int r = 0; r < 4; ++r) {
        const float y = (float)acc[ct][ht][r] * fac[ct][r];
        const float q = fminf(fmaxf(rintf(y / sf2), -128.f), 127.f);
        q2[(w * 32 + ct * 16 + g * 4 + r) * 116 + ht * 16 + m] = (_Float16)q;
      }
  __syncthreads();
  const long obase = (long)n * 100352 + tt * 28;
  for (int i = t; i < 3584; i += 256) {
    const unsigned co = (unsigned)i / 28u;
    const unsigned wo = (unsigned)i - co * 28u;
    const _Float16* row = q2 + co * 116;
    const float a = (float)row[2 * wo] + (float)row[2 * wo + 1] +
                    (float)row[56 + 2 * wo] + (float)row[56 + 2 * wo + 1];
    out[obase + (long)co * 784 + wo] = rintf(a * 0.25f) * sf2;
  }
}

extern "C" void kernel_launch(void* const* d_in, const int* in_sizes, int n_in,
                              void* d_out, int out_size, void* d_ws, size_t ws_size,
                              hipStream_t stream) {
  const float* x     = (const float*)d_in[0];
  const float* actsf = (const float*)d_in[1];
  const float* bnw   = (const float*)d_in[2];
  const float* bnb   = (const float*)d_in[3];
  const float* bnm   = (const float*)d_in[4];
  const float* bnv   = (const float*)d_in[5];
  const float* cw    = (const float*)d_in[6];
  float* out = (float*)d_out;
  char* ws = (char*)d_ws;

  unsigned* chanKmx   = (unsigned*)(ws + 256);         // 1 KB  (zeroed by k0_zero)
  unsigned* chanKmn   = (unsigned*)(ws + 1280);        // 1 KB  (zeroed by k0_zero)
  float* scq          = (float*)(ws + 4096);           // 1 KB
  float* shq          = (float*)(ws + 5120);           // 1 KB
  float* wsf          = (float*)(ws + 6144);           // 512 B
  signed char* wq8    = (signed char*)(ws + 8192);     // 32 KB
  float* blockmax     = (float*)(ws + 40960);          // 3136 f32 (12.5 KB)
  signed char* xqT    = (signed char*)(ws + 65536);    // 51.4 MB (N,HW,C int8)
  float* outsf2       = out + (out_size - 1);

  hipLaunchKernelGGL(k0_zero, dim3(1), dim3(256), 0, stream, (unsigned*)ws);
  hipLaunchKernelGGL(k1_minmax, dim3(2049), dim3(256), 0, stream,
                     x, actsf, bnw, bnb, bnm, bnv, cw, chanKmx, chanKmn, scq, shq, wsf, wq8);
  hipLaunchKernelGGL(k2f_quant_gemm, dim3(3136), dim3(256), 0, stream,
                     x, scq, shq, chanKmx, chanKmn, wq8, wsf, xqT, blockmax);
  hipLaunchKernelGGL(k3_final, dim3(1792), dim3(256), 0, stream,
                     xqT, wq8, wsf, scq, shq, chanKmx, chanKmn, blockmax, out, outsf2);
}

// Round 11
// 151.603 us; speedup vs baseline: 3.0084x; 1.0361x over previous
//
#include <hip/hip_runtime.h>

#define QMAXF 127.0f
typedef int i32x4 __attribute__((ext_vector_type(4)));

__device__ __forceinline__ unsigned fkey(float f) {
  const unsigned b = __float_as_uint(f);
  return (b & 0x80000000u) ? ~b : (b | 0x80000000u);
}
__device__ __forceinline__ float fdec(unsigned u) {
  return __uint_as_float((u & 0x80000000u) ? (u & 0x7FFFFFFFu) : ~u);
}

// ===== k0_zero: zero the atomic/flag region =====
__global__ __launch_bounds__(256) void k0_zero(unsigned* __restrict__ p) {
  const int t = threadIdx.x;
  p[t] = 0u; p[t + 256] = 0u; p[t + 512] = 0u; p[t + 768] = 0u;
}

// ===== k1: per-channel min/max of x (blocks 0..2047) + prep (block 2048) =====
__global__ __launch_bounds__(256, 8) void k1_minmax(
    const float* __restrict__ x, const float* __restrict__ actsf,
    const float* __restrict__ bnw, const float* __restrict__ bnb,
    const float* __restrict__ bnm, const float* __restrict__ bnv,
    const float* __restrict__ cw, unsigned* __restrict__ chanKmx,
    unsigned* __restrict__ chanKmn, float* __restrict__ scq,
    float* __restrict__ shq, float* __restrict__ wsf,
    signed char* __restrict__ wq8) {
  const int t = threadIdx.x, b = blockIdx.x;
  if (b == 2048) {
    // ---- BN fold: thread = channel ----
    __shared__ float red[4];
    float scale, shift;
    {
#pragma clang fp contract(off)
      float inv = 1.0f / sqrtf(bnv[t] + 1e-5f);
      scale = bnw[t] * inv;
      float tmp = bnm[t] * scale;
      shift = bnb[t] - tmp;
    }
    float a = fabsf(scale);
    for (int o = 32; o > 0; o >>= 1) a = fmaxf(a, __shfl_xor(a, o));
    if ((t & 63) == 0) red[t >> 6] = a;
    __syncthreads();
    const float amax = fmaxf(fmaxf(red[0], red[1]), fmaxf(red[2], red[3]));
    const float bn_sf = amax / QMAXF;
    scq[t] = fminf(fmaxf(rintf(scale / bn_sf), -128.f), 127.f) * bn_sf;
    const float bias_sf = bn_sf * actsf[0];
    shq[t] = rintf(shift / bias_sf) * bias_sf;
    // ---- weight quant: 2 threads per output row ----
    const int r = t >> 1, half = t & 1;
    const float4* wrow = (const float4*)(cw + r * 256 + half * 128);
    float mx = 0.f;
#pragma unroll
    for (int j = 0; j < 32; ++j) {
      const float4 v = wrow[j];
      mx = fmaxf(mx, fmaxf(fmaxf(fabsf(v.x), fabsf(v.y)), fmaxf(fabsf(v.z), fabsf(v.w))));
    }
    mx = fmaxf(mx, __shfl_xor(mx, 1));
    const float wsf_v = mx / QMAXF;
    if (half == 0) wsf[r] = wsf_v;
    int* w8w = (int*)wq8;
#pragma unroll
    for (int j = 0; j < 32; ++j) {
      const float4 v = wrow[j];
      const float q0 = fminf(fmaxf(rintf(v.x / wsf_v), -128.f), 127.f);
      const float q1 = fminf(fmaxf(rintf(v.y / wsf_v), -128.f), 127.f);
      const float q2 = fminf(fmaxf(rintf(v.z / wsf_v), -128.f), 127.f);
      const float q3 = fminf(fmaxf(rintf(v.w / wsf_v), -128.f), 127.f);
      w8w[r * 64 + half * 32 + j] =
          ((int)q0 & 255) | (((int)q1 & 255) << 8) | (((int)q2 & 255) << 16) | (((int)q3 & 255) << 24);
    }
    return;
  }
  // ---- per-channel raw min/max: block = (n, 8-channel group) ----
  __shared__ float redmn[4][8], redmx[4][8];
  const int n = b >> 5, cg = b & 31;
  const float4* __restrict__ x4 = (const float4*)x + (long)(n * 256 + cg * 8) * 784;
  float mn[8], mx[8];
#pragma unroll
  for (int r = 0; r < 8; ++r) { mn[r] = __builtin_inff(); mx[r] = -__builtin_inff(); }
#pragma unroll
  for (int r = 0; r < 8; ++r) {
    const float4* row = x4 + r * 784;
    for (int j = t; j < 784; j += 256) {
      const float4 v = row[j];
      mn[r] = fminf(mn[r], fminf(fminf(v.x, v.y), fminf(v.z, v.w)));
      mx[r] = fmaxf(mx[r], fmaxf(fmaxf(v.x, v.y), fmaxf(v.z, v.w)));
    }
  }
#pragma unroll
  for (int r = 0; r < 8; ++r)
    for (int o = 32; o > 0; o >>= 1) {
      mn[r] = fminf(mn[r], __shfl_xor(mn[r], o));
      mx[r] = fmaxf(mx[r], __shfl_xor(mx[r], o));
    }
  if ((t & 63) == 0) {
#pragma unroll
    for (int r = 0; r < 8; ++r) { redmn[t >> 6][r] = mn[r]; redmx[t >> 6][r] = mx[r]; }
  }
  __syncthreads();
  if (t < 8) {
    const float fmn = fminf(fminf(redmn[0][t], redmn[1][t]), fminf(redmn[2][t], redmn[3][t]));
    const float fmx = fmaxf(fmaxf(redmx[0][t], redmx[1][t]), fmaxf(redmx[2][t], redmx[3][t]));
    atomicMax(&chanKmx[cg * 8 + t], fkey(fmx));
    atomicMax(&chanKmn[cg * 8 + t], ~fkey(fmn));
  }
}

// ===== k2f: CONTIGUOUS-read quantize + LDS byte-transpose + xqT + int8 MFMA + blockmax =====
// Block = (n, tt): 112 hw x 256 ci tile. Reads walk hw within each channel (448B runs).
// LDS tile: bytes [hw][256 ci], ci XOR-swizzled by ((hw>>2)&15)<<4 (16B-block granular).
__global__ __launch_bounds__(256, 4) void k2f_quant_gemm(
    const float* __restrict__ x, const float* __restrict__ scq,
    const float* __restrict__ shq, const unsigned* __restrict__ chanKmx,
    const unsigned* __restrict__ chanKmn, const signed char* __restrict__ wq8,
    const float* __restrict__ wsf, signed char* __restrict__ xqT,
    float* __restrict__ blockmax) {
  __shared__ __align__(16) unsigned char ldsb[112 * 256];  // 28 KB
  __shared__ float s_scq[256], s_shq[256];
  __shared__ float comax[128];
  __shared__ float red[4];
  __shared__ float sf1s;
  const int t = threadIdx.x, w = t >> 6, l = t & 63, m = l & 15, g = l >> 4;
  const int blk = blockIdx.x, n = blk / 28, tt = blk - n * 28;

  // ---- preload scales + sf1 from channel extremes (exact: z monotone in x per channel) ----
  {
    const float s = scq[t], sh = shq[t];
    s_scq[t] = s; s_shq[t] = sh;
    const float xe = (s >= 0.f) ? fdec(chanKmx[t]) : fdec(~chanKmn[t]);
    float z;
    {
#pragma clang fp contract(off)
      z = xe * s + sh;
    }
    float mm = fmaxf(z, 0.f);
    for (int o = 32; o > 0; o >>= 1) mm = fmaxf(mm, __shfl_xor(mm, o));
    if (l == 0) red[w] = mm;
    __syncthreads();
    if (t == 0) sf1s = fmaxf(fmaxf(red[0], red[1]), fmaxf(red[2], red[3])) / QMAXF;
    __syncthreads();
  }
  const float sf1 = sf1s;
  const float* __restrict__ xb = x + (long)n * 802816 + tt * 112;

  // ---- quantize: 28 iters, contiguous 448B runs per channel ----
  for (int it = 0; it < 28; ++it) {
    const int idx = it * 256 + t;        // 0..7167
    const int c = idx / 28;              // channel 0..255
    const int p = idx - c * 28;          // float4 position (hw = 4p)
    const float4 v = *(const float4*)(xb + (long)c * 3136 + 4 * p);
    const float s = s_scq[c], sh = s_shq[c];
    float z0, z1, z2, z3;
    {
#pragma clang fp contract(off)
      z0 = v.x * s + sh; z1 = v.y * s + sh; z2 = v.z * s + sh; z3 = v.w * s + sh;
    }
    const float q0 = fminf(fmaxf(rintf(fmaxf(z0, 0.f) / sf1), -128.f), 127.f);
    const float q1 = fminf(fmaxf(rintf(fmaxf(z1, 0.f) / sf1), -128.f), 127.f);
    const float q2 = fminf(fmaxf(rintf(fmaxf(z2, 0.f) / sf1), -128.f), 127.f);
    const float q3 = fminf(fmaxf(rintf(fmaxf(z3, 0.f) / sf1), -128.f), 127.f);
    const int cs = c ^ ((p & 15) << 4);  // swizzled ci column (hw>>2 == p)
    const int hw0 = 4 * p;
    ldsb[(hw0 + 0) * 256 + cs] = (unsigned char)((int)q0 & 255);
    ldsb[(hw0 + 1) * 256 + cs] = (unsigned char)((int)q1 & 255);
    ldsb[(hw0 + 2) * 256 + cs] = (unsigned char)((int)q2 & 255);
    ldsb[(hw0 + 3) * 256 + cs] = (unsigned char)((int)q3 & 255);
  }
  __syncthreads();

  // ---- xqT writeback: 4KB-contiguous per wave ----
  signed char* __restrict__ dst = xqT + ((long)(n * 3136 + tt * 112)) * 256;
#pragma unroll
  for (int it = 0; it < 7; ++it) {
    const int idx = it * 256 + t;
    const int hw = idx >> 4, c16 = idx & 15;
    const i32x4 v = *(const i32x4*)&ldsb[hw * 256 + ((c16 * 16) ^ (((hw >> 2) & 15) << 4))];
    *(i32x4*)(dst + hw * 256 + c16 * 16) = v;
  }

  // ---- int8 MFMA from LDS: 7 ht x 2 ct x 4 ks ----
  i32x4 acc[2][7];
#pragma unroll
  for (int ct = 0; ct < 2; ++ct)
#pragma unroll
    for (int ht = 0; ht < 7; ++ht) acc[ct][ht] = (i32x4){0, 0, 0, 0};
#pragma unroll
  for (int ks = 0; ks < 4; ++ks) {
    const i32x4 wf0 = *(const i32x4*)(wq8 + (w * 32 + m) * 256 + ks * 64 + g * 16);
    const i32x4 wf1 = *(const i32x4*)(wq8 + (w * 32 + 16 + m) * 256 + ks * 64 + g * 16);
#pragma unroll
    for (int ht = 0; ht < 7; ++ht) {
      const int row = ht * 16 + m;
      const i32x4 xf = *(const i32x4*)&ldsb[row * 256 +
                          ((ks * 64 + g * 16) ^ (((row >> 2) & 15) << 4))];
      acc[0][ht] = __builtin_amdgcn_mfma_i32_16x16x64_i8(wf0, xf, acc[0][ht], 0, 0, 0);
      acc[1][ht] = __builtin_amdgcn_mfma_i32_16x16x64_i8(wf1, xf, acc[1][ht], 0, 0, 0);
    }
  }

  // ---- per-co |y_int| max -> scaled -> private blockmax slot ----
  int im[2][4];
#pragma unroll
  for (int ct = 0; ct < 2; ++ct)
#pragma unroll
    for (int r = 0; r < 4; ++r) {
      int v = 0;
#pragma unroll
      for (int ht = 0; ht < 7; ++ht) {
        int a = acc[ct][ht][r];
        a = a < 0 ? -a : a;
        v = a > v ? a : v;
      }
      im[ct][r] = v;
    }
#pragma unroll
  for (int o = 1; o < 16; o <<= 1)
#pragma unroll
    for (int ct = 0; ct < 2; ++ct)
#pragma unroll
      for (int r = 0; r < 4; ++r) {
        const int other = __shfl_xor(im[ct][r], o);
        im[ct][r] = other > im[ct][r] ? other : im[ct][r];
      }
  if (m == 0) {
#pragma unroll
    for (int ct = 0; ct < 2; ++ct)
#pragma unroll
      for (int r = 0; r < 4; ++r)
        comax[w * 32 + ct * 16 + g * 4 + r] = (float)im[ct][r];
  }
  __syncthreads();
  float v = 0.f;
  if (t < 128) v = comax[t] * (sf1 * wsf[t]);
  for (int o = 32; o > 0; o >>= 1) v = fmaxf(v, __shfl_xor(v, o));
  if (l == 0) red[w] = v;
  __syncthreads();
  if (t == 0)
    blockmax[blk] = fmaxf(fmaxf(red[0], red[1]), fmaxf(red[2], red[3]));
}

// ===== k3: blockmax reduce + final int8 GEMM + requant + fused 2x2 pool =====
__global__ __launch_bounds__(256, 3) void k3_final(
    const signed char* __restrict__ xqT, const signed char* __restrict__ wq8,
    const float* __restrict__ wsf, const float* __restrict__ scq,
    const float* __restrict__ shq, const unsigned* __restrict__ chanKmx,
    const unsigned* __restrict__ chanKmn, const float* __restrict__ blockmax,
    float* __restrict__ out, float* __restrict__ outsf2) {
  __shared__ _Float16 q2[128 * 116];  // 29.75 KB
  __shared__ float red[4];
  __shared__ float sf1s, sf2s;
  const int t = threadIdx.x, w = t >> 6, l = t & 63;
  const int m = l & 15, g = l >> 4;
  const int blk = blockIdx.x;
  const int n = blk / 28, tt = blk - n * 28;

  // ---- recompute sf1 (identical arithmetic to k2f) ----
  {
    const float s = scq[t], sh = shq[t];
    const float xe = (s >= 0.f) ? fdec(chanKmx[t]) : fdec(~chanKmn[t]);
    float z;
    {
#pragma clang fp contract(off)
      z = xe * s + sh;
    }
    float mm = fmaxf(z, 0.f);
    for (int o = 32; o > 0; o >>= 1) mm = fmaxf(mm, __shfl_xor(mm, o));
    if (l == 0) red[w] = mm;
    __syncthreads();
    if (t == 0) sf1s = fmaxf(fmaxf(red[0], red[1]), fmaxf(red[2], red[3])) / QMAXF;
  }
  // ---- sf2 = max over 1792 block maxima (L2-hot) ----
  {
    float bm = 0.f;
    for (int i = t; i < 1792; i += 256) bm = fmaxf(bm, blockmax[i]);
    for (int o = 32; o > 0; o >>= 1) bm = fmaxf(bm, __shfl_xor(bm, o));
    __syncthreads();
    if (l == 0) red[w] = bm;
    __syncthreads();
    if (t == 0) sf2s = fmaxf(fmaxf(red[0], red[1]), fmaxf(red[2], red[3])) / QMAXF;
    __syncthreads();
  }
  const float sf1 = sf1s;
  const float sf2 = sf2s;
  if (blk == 0 && t == 0) outsf2[0] = sf2;

  const signed char* __restrict__ xb = xqT + ((long)(n * 3136 + tt * 112)) * 256;
  i32x4 acc[2][7];
#pragma unroll
  for (int ct = 0; ct < 2; ++ct)
#pragma unroll
    for (int ht = 0; ht < 7; ++ht) acc[ct][ht] = (i32x4){0, 0, 0, 0};
#pragma unroll
  for (int ks = 0; ks < 4; ++ks) {
    const i32x4 wf0 = *(const i32x4*)(wq8 + (w * 32 + m) * 256 + ks * 64 + g * 16);
    const i32x4 wf1 = *(const i32x4*)(wq8 + (w * 32 + 16 + m) * 256 + ks * 64 + g * 16);
#pragma unroll
    for (int ht = 0; ht < 7; ++ht) {
      const i32x4 xf = *(const i32x4*)(xb + (ht * 16 + m) * 256 + ks * 64 + g * 16);
      acc[0][ht] = __builtin_amdgcn_mfma_i32_16x16x64_i8(wf0, xf, acc[0][ht], 0, 0, 0);
      acc[1][ht] = __builtin_amdgcn_mfma_i32_16x16x64_i8(wf1, xf, acc[1][ht], 0, 0, 0);
    }
  }
  float fac[2][4];
#pragma unroll
  for (int ct = 0; ct < 2; ++ct)
#pragma unroll
    for (int r = 0; r < 4; ++r)
      fac[ct][r] = sf1 * wsf[w * 32 + ct * 16 + g * 4 + r];
#pragma unroll
  for (int ct = 0; ct < 2; ++ct)
#pragma unroll
    for (int ht = 0; ht < 7; ++ht)
#pragma unroll
      for (int r = 0; r < 4; ++r) {
        const float y = (float)acc[ct][ht][r] * fac[ct][r];
        const float q = fminf(fmaxf(rintf(y / sf2), -128.f), 127.f);
        q2[(w * 32 + ct * 16 + g * 4 + r) * 116 + ht * 16 + m] = (_Float16)q;
      }
  __syncthreads();
  const long obase = (long)n * 100352 + tt * 28;
  for (int i = t; i < 3584; i += 256) {
    const unsigned co = (unsigned)i / 28u;
    const unsigned wo = (unsigned)i - co * 28u;
    const _Float16* row = q2 + co * 116;
    const float a = (float)row[2 * wo] + (float)row[2 * wo + 1] +
                    (float)row[56 + 2 * wo] + (float)row[56 + 2 * wo + 1];
    out[obase + (long)co * 784 + wo] = rintf(a * 0.25f) * sf2;
  }
}

extern "C" void kernel_launch(void* const* d_in, const int* in_sizes, int n_in,
                              void* d_out, int out_size, void* d_ws, size_t ws_size,
                              hipStream_t stream) {
  const float* x     = (const float*)d_in[0];
  const float* actsf = (const float*)d_in[1];
  const float* bnw   = (const float*)d_in[2];
  const float* bnb   = (const float*)d_in[3];
  const float* bnm   = (const float*)d_in[4];
  const float* bnv   = (const float*)d_in[5];
  const float* cw    = (const float*)d_in[6];
  float* out = (float*)d_out;
  char* ws = (char*)d_ws;

  unsigned* chanKmx   = (unsigned*)(ws + 256);         // 1 KB  (zeroed by k0_zero)
  unsigned* chanKmn   = (unsigned*)(ws + 1280);        // 1 KB  (zeroed by k0_zero)
  float* scq          = (float*)(ws + 4096);           // 1 KB
  float* shq          = (float*)(ws + 5120);           // 1 KB
  float* wsf          = (float*)(ws + 6144);           // 512 B
  signed char* wq8    = (signed char*)(ws + 8192);     // 32 KB
  float* blockmax     = (float*)(ws + 40960);          // 1792 f32
  signed char* xqT    = (signed char*)(ws + 65536);    // 51.4 MB (N,HW,C int8)
  float* outsf2       = out + (out_size - 1);

  hipLaunchKernelGGL(k0_zero, dim3(1), dim3(256), 0, stream, (unsigned*)ws);
  hipLaunchKernelGGL(k1_minmax, dim3(2049), dim3(256), 0, stream,
                     x, actsf, bnw, bnb, bnm, bnv, cw, chanKmx, chanKmn, scq, shq, wsf, wq8);
  hipLaunchKernelGGL(k2f_quant_gemm, dim3(1792), dim3(256), 0, stream,
                     x, scq, shq, chanKmx, chanKmn, wq8, wsf, xqT, blockmax);
  hipLaunchKernelGGL(k3_final, dim3(1792), dim3(256), 0, stream,
                     xqT, wq8, wsf, scq, shq, chanKmx, chanKmn, blockmax, out, outsf2);
}